// Round 11
// baseline (531.918 us; speedup 1.0000x reference)
//
#include <hip/hip_runtime.h>

#define B_ROWS 32768
#define D_IN   512
#define H1_N   256
#define H2_N   128
#define LAT_N  64
#define K_CB   2048

#define VQ_MARGIN 6.0e-3f
#define BK 32
#define BN 128

typedef __attribute__((ext_vector_type(8))) short s8v;   // 8 bf16 (4 VGPRs)
typedef __attribute__((ext_vector_type(4))) float f4v;   // 4 f32 acc

__device__ inline unsigned short f2bf(float f) {
    union { float f; unsigned u; } v; v.f = f;
    unsigned r = v.u + 0x7fffu + ((v.u >> 16) & 1u);
    return (unsigned short)(r >> 16);
}
__device__ inline float bf2f(unsigned short h) {
    union { unsigned u; float f; } v; v.u = ((unsigned)h) << 16;
    return v.f;
}

// XOR swizzle for k-major LDS A-tiles (valid within 8-float groups)
#define SWZ(row) ((((row) >> 2) & 7) << 3)

// ---------------- universal MFMA GEMM (bf16x3, double-buffered K loop) ---
// Block = 256 thr = 2x2 waves; wave tile = (RT*16) x (CT*16).
// MODE 0: v = BN(ReLU(A@W+b)) -> out_hi/out_lo
// MODE 2: v = A@W+b -> out_f32, + (v-xref)^2 partials
// MODE 3: v = A@W+b -> out_f32 AND out_hi/out_lo
template <int MODE, int K, int RT, int CT, bool ASPLIT>
__global__ __launch_bounds__(256, (CT >= 4) ? 3 : 4) void mfma_gemm(
    const float* __restrict__ A_f32,
    const unsigned short* __restrict__ A_hi,
    const unsigned short* __restrict__ A_lo,
    const unsigned short* __restrict__ w_hi,
    const unsigned short* __restrict__ w_lo,
    const float* __restrict__ bias,
    const float* __restrict__ bn_g, const float* __restrict__ bn_b,
    const float* __restrict__ bn_m, const float* __restrict__ bn_v,
    unsigned short* __restrict__ out_hi, unsigned short* __restrict__ out_lo,
    float* __restrict__ out_f32,
    const float* __restrict__ xref, float* __restrict__ partials, int N)
{
    constexpr int NK = K / 32;           // even for all layers used
    const int lane = threadIdx.x & 63;
    const int wv = threadIdx.x >> 6;
    const int wr = wv >> 1, wc = wv & 1;
    const int rbase = blockIdx.x * (RT * 32) + wr * (RT * 16);
    const int cbase = blockIdx.y * (CT * 32) + wc * (CT * 16);
    const int lr = lane & 15, lg = lane >> 4;

    f4v acc[RT][CT];
#pragma unroll
    for (int rt = 0; rt < RT; ++rt)
#pragma unroll
        for (int ct = 0; ct < CT; ++ct)
            acc[rt][ct] = (f4v){0.f, 0.f, 0.f, 0.f};

    s8v ahA[RT], alA[RT], bhA[CT], blA[CT];
    s8v ahB[RT], alB[RT], bhB[CT], blB[CT];
    float4 rwA[RT][2], rwB[RT][2];

#define LOAD_A(S, KS)                                                         \
    {                                                                         \
        _Pragma("unroll")                                                     \
        for (int rt = 0; rt < RT; ++rt) {                                     \
            size_t aoff = (size_t)(rbase + rt * 16 + lr) * K + (KS) * 32 + lg * 8; \
            if constexpr (ASPLIT) {                                           \
                rw##S[rt][0] = *reinterpret_cast<const float4*>(&A_f32[aoff]);      \
                rw##S[rt][1] = *reinterpret_cast<const float4*>(&A_f32[aoff + 4]);  \
            } else {                                                          \
                ah##S[rt] = *reinterpret_cast<const s8v*>(&A_hi[aoff]);       \
                al##S[rt] = *reinterpret_cast<const s8v*>(&A_lo[aoff]);       \
            }                                                                 \
        }                                                                     \
    }

#define LOAD_B(S, KS)                                                         \
    {                                                                         \
        _Pragma("unroll")                                                     \
        for (int ct = 0; ct < CT; ++ct) {                                     \
            size_t woff = (size_t)(cbase + ct * 16 + lr) * K + (KS) * 32 + lg * 8; \
            bh##S[ct] = *reinterpret_cast<const s8v*>(&w_hi[woff]);           \
            bl##S[ct] = *reinterpret_cast<const s8v*>(&w_lo[woff]);           \
        }                                                                     \
    }

#define CONVERT(S)                                                            \
    if constexpr (ASPLIT) {                                                   \
        _Pragma("unroll")                                                     \
        for (int rt = 0; rt < RT; ++rt) {                                     \
            float fv[8] = {rw##S[rt][0].x, rw##S[rt][0].y, rw##S[rt][0].z,    \
                           rw##S[rt][0].w, rw##S[rt][1].x, rw##S[rt][1].y,    \
                           rw##S[rt][1].z, rw##S[rt][1].w};                   \
            unsigned uu[8], llv[8];                                           \
            _Pragma("unroll")                                                 \
            for (int j = 0; j < 8; ++j) {                                     \
                uu[j] = __float_as_uint(fv[j]);                               \
                float lo = fv[j] - __uint_as_float(uu[j] & 0xffff0000u);      \
                llv[j] = __float_as_uint(lo);                                 \
            }                                                                 \
            union { s8v v; unsigned w[4]; } Hh, Ll;                           \
            _Pragma("unroll")                                                 \
            for (int m = 0; m < 4; ++m) {                                     \
                Hh.w[m] = __builtin_amdgcn_perm(uu[2 * m + 1], uu[2 * m], 0x07060302u);   \
                Ll.w[m] = __builtin_amdgcn_perm(llv[2 * m + 1], llv[2 * m], 0x07060302u); \
            }                                                                 \
            ah##S[rt] = Hh.v;                                                 \
            al##S[rt] = Ll.v;                                                 \
        }                                                                     \
    }

#define MFMA_STEP(S)                                                          \
    {                                                                         \
        _Pragma("unroll")                                                     \
        for (int rt = 0; rt < RT; ++rt)                                       \
            _Pragma("unroll")                                                 \
            for (int ct = 0; ct < CT; ++ct) {                                 \
                acc[rt][ct] = __builtin_amdgcn_mfma_f32_16x16x32_bf16(        \
                    ah##S[rt], bh##S[ct], acc[rt][ct], 0, 0, 0);              \
                acc[rt][ct] = __builtin_amdgcn_mfma_f32_16x16x32_bf16(        \
                    al##S[rt], bh##S[ct], acc[rt][ct], 0, 0, 0);              \
                acc[rt][ct] = __builtin_amdgcn_mfma_f32_16x16x32_bf16(        \
                    ah##S[rt], bl##S[ct], acc[rt][ct], 0, 0, 0);              \
            }                                                                 \
    }

    LOAD_A(A, 0); LOAD_B(A, 0); CONVERT(A);
#pragma unroll
    for (int k2 = 0; k2 < NK / 2; ++k2) {
        LOAD_A(B, 2 * k2 + 1); LOAD_B(B, 2 * k2 + 1);
        MFMA_STEP(A);
        CONVERT(B);
        if (k2 + 1 < NK / 2) { LOAD_A(A, 2 * k2 + 2); LOAD_B(A, 2 * k2 + 2); }
        MFMA_STEP(B);
        if (k2 + 1 < NK / 2) CONVERT(A);
    }
#undef LOAD_A
#undef LOAD_B
#undef CONVERT
#undef MFMA_STEP

    float sq = 0.f;
#pragma unroll
    for (int ct = 0; ct < CT; ++ct) {
        int col = cbase + ct * 16 + lr;
        float bi = bias[col];
        float sc = 0.f, sh = 0.f;
        if (MODE == 0) {
            float s = bn_g[col] * rsqrtf(bn_v[col] + 1e-5f);
            sc = s;
            sh = bn_b[col] - bn_m[col] * s;
        }
#pragma unroll
        for (int rt = 0; rt < RT; ++rt)
#pragma unroll
            for (int i = 0; i < 4; ++i) {
                int row = rbase + rt * 16 + lg * 4 + i;
                float v = acc[rt][ct][i] + bi;
                if (MODE == 0) v = fmaxf(v, 0.f) * sc + sh;
                if (MODE == 0 || MODE == 3) {
                    unsigned u = __float_as_uint(v);
                    out_hi[(size_t)row * N + col] = (unsigned short)(u >> 16);
                    out_lo[(size_t)row * N + col] =
                        f2bf(v - __uint_as_float(u & 0xffff0000u));
                }
                if (MODE == 2) {
                    float d = v - xref[(size_t)row * N + col];
                    sq = fmaf(d, d, sq);
                }
                if (MODE == 2 || MODE == 3)
                    out_f32[(size_t)row * N + col] = v;
            }
    }
    if (MODE == 2) {
        __shared__ float red[256];
        red[threadIdx.x] = sq;
        __syncthreads();
        for (int off = 128; off > 0; off >>= 1) {
            if (threadIdx.x < off) red[threadIdx.x] += red[threadIdx.x + off];
            __syncthreads();
        }
        if (threadIdx.x == 0)
            partials[blockIdx.y * gridDim.x + blockIdx.x] = red[0];
    }
}

// ---- f32 GEMM for flagged-row repair (64x128 tile, dynamic M, gather) ---
template <int MODE, bool GATHER>
__global__ __launch_bounds__(256, 6) void rgemm(
    const int* __restrict__ rcnt, const int* __restrict__ rlist,
    const float* __restrict__ A, const float* __restrict__ W,
    const float* __restrict__ bias,
    const float* __restrict__ bn_g, const float* __restrict__ bn_b,
    const float* __restrict__ bn_m, const float* __restrict__ bn_v,
    float* __restrict__ out, int M, int N)
{
    const int count = min(rcnt[0], B_ROWS);
    const int row0 = blockIdx.x * 64;
    if (row0 >= count) return;
    __shared__ float sA[BK][64];
    __shared__ float sB[BK][BN];
    const int tid = threadIdx.x;
    const int tr = tid >> 4;
    const int tc = tid & 15;
    const int n0 = blockIdx.y * BN;

    float acc[4][8];
#pragma unroll
    for (int i = 0; i < 4; ++i)
#pragma unroll
        for (int j = 0; j < 8; ++j) acc[i][j] = 0.f;

    for (int k0 = 0; k0 < M; k0 += BK) {
#pragma unroll
        for (int it = 0; it < 2; ++it) {
            int s = tid + it * 256;
            int m = s >> 3;
            int kq = s & 7;
            int i = row0 + m;
            int src;
            if (GATHER) {
                int rr = (i < count) ? rlist[i] : 0;
                src = ((unsigned)rr < (unsigned)B_ROWS) ? rr : 0;
            } else {
                src = i;
            }
            float4 v = *reinterpret_cast<const float4*>(
                &A[(size_t)src * M + k0 + kq * 4]);
            int kk = kq * 4;
            sA[kk + 0][m ^ SWZ(kk + 0)] = v.x;
            sA[kk + 1][m ^ SWZ(kk + 1)] = v.y;
            sA[kk + 2][m ^ SWZ(kk + 2)] = v.z;
            sA[kk + 3][m ^ SWZ(kk + 3)] = v.w;
        }
#pragma unroll
        for (int it = 0; it < 4; ++it) {
            int s = tid + it * 256;
            int k = s >> 5;
            int nq = s & 31;
            int n = n0 + nq * 4;
            float4 v = make_float4(0.f, 0.f, 0.f, 0.f);
            if (n < N)
                v = *reinterpret_cast<const float4*>(&W[(size_t)(k0 + k) * N + n]);
            *reinterpret_cast<float4*>(&sB[k][nq * 4]) = v;
        }
        __syncthreads();
#pragma unroll 4
        for (int k = 0; k < BK; ++k) {
            int ac = (tr * 4) ^ SWZ(k);
            float4 a0 = *reinterpret_cast<float4*>(&sA[k][ac]);
            float a[4] = {a0.x, a0.y, a0.z, a0.w};
            float4 b0 = *reinterpret_cast<float4*>(&sB[k][tc * 4]);
            float4 b1 = *reinterpret_cast<float4*>(&sB[k][64 + tc * 4]);
            float b[8] = {b0.x, b0.y, b0.z, b0.w, b1.x, b1.y, b1.z, b1.w};
#pragma unroll
            for (int i = 0; i < 4; ++i)
#pragma unroll
                for (int j = 0; j < 8; ++j)
                    acc[i][j] = fmaf(a[i], b[j], acc[i][j]);
        }
        __syncthreads();
    }

    const int nb0 = n0 + tc * 4;
    const int nb1 = n0 + 64 + tc * 4;
    float bi[8], sc[8], sh[8];
#pragma unroll
    for (int g = 0; g < 2; ++g) {
        int nb = g ? nb1 : nb0;
        if (nb < N) {
#pragma unroll
            for (int j = 0; j < 4; ++j) {
                int n = nb + j;
                bi[g * 4 + j] = bias[n];
                if (MODE == 0) {
                    float s = bn_g[n] * rsqrtf(bn_v[n] + 1e-5f);
                    sc[g * 4 + j] = s;
                    sh[g * 4 + j] = bn_b[n] - bn_m[n] * s;
                }
            }
        }
    }
#pragma unroll
    for (int i = 0; i < 4; ++i) {
        int row = row0 + tr * 4 + i;
#pragma unroll
        for (int g = 0; g < 2; ++g) {
            int nb = g ? nb1 : nb0;
            if (nb < N) {
                float o[4];
#pragma unroll
                for (int j = 0; j < 4; ++j) {
                    float v = acc[i][g * 4 + j] + bi[g * 4 + j];
                    if (MODE == 0) {
                        v = v > 0.f ? v : 0.f;
                        v = v * sc[g * 4 + j] + sh[g * 4 + j];
                    }
                    o[j] = v;
                }
                *reinterpret_cast<float4*>(&out[(size_t)row * N + nb]) =
                    make_float4(o[0], o[1], o[2], o[3]);
            }
        }
    }
}

// ---------------- fused prep: weight splits + codebook + zero counters ---
__device__ inline void wprep_body(const float* __restrict__ w,
                                  unsigned short* __restrict__ w_hi,
                                  unsigned short* __restrict__ w_lo,
                                  int K, int N, int idx)
{
    if (idx >= N * K) return;
    int n = idx / K, k = idx - n * K;
    float f = w[(size_t)k * N + n];
    unsigned u = __float_as_uint(f);
    float lo = f - __uint_as_float(u & 0xffff0000u);
    w_hi[idx] = (unsigned short)(u >> 16);
    w_lo[idx] = f2bf(lo);
}

__global__ __launch_bounds__(256) void prep_all(
    const float* __restrict__ dw3, unsigned short* w3hi, unsigned short* w3lo,
    const float* __restrict__ dw2, unsigned short* w2hi, unsigned short* w2lo,
    const float* __restrict__ dw1, unsigned short* w1hi, unsigned short* w1lo,
    const float* __restrict__ ew1, unsigned short* e1hi, unsigned short* e1lo,
    const float* __restrict__ ew2, unsigned short* e2hi, unsigned short* e2lo,
    const float* __restrict__ ew3, unsigned short* e3hi, unsigned short* e3lo,
    const float* __restrict__ cb, unsigned short* cb_hi, unsigned short* cb_lo,
    float* __restrict__ cn, int* __restrict__ rcnt, float* __restrict__ repairp)
{
    int bid = blockIdx.x;
    int tid = threadIdx.x;
    if (bid < 512) {
        wprep_body(dw3, w3hi, w3lo, H1_N, D_IN, bid * 256 + tid);
    } else if (bid < 640) {
        wprep_body(dw2, w2hi, w2lo, H2_N, H1_N, (bid - 512) * 256 + tid);
    } else if (bid < 672) {
        wprep_body(dw1, w1hi, w1lo, LAT_N, H2_N, (bid - 640) * 256 + tid);
    } else if (bid < 1184) {
        wprep_body(ew1, e1hi, e1lo, D_IN, H1_N, (bid - 672) * 256 + tid);
    } else if (bid < 1312) {
        wprep_body(ew2, e2hi, e2lo, H1_N, H2_N, (bid - 1184) * 256 + tid);
    } else if (bid < 1344) {
        wprep_body(ew3, e3hi, e3lo, H2_N, LAT_N, (bid - 1312) * 256 + tid);
    } else {
        int blk = bid - 1344;
        if (blk == 0) {
            if (tid == 0) rcnt[0] = 0;
            repairp[tid] = 0.f;
        }
        int j = blk * 256 + tid;
        float s = 0.f;
#pragma unroll
        for (int lq = 0; lq < 16; ++lq) {
            float4 v = *reinterpret_cast<const float4*>(&cb[(size_t)j * LAT_N + lq * 4]);
            float e[4] = {v.x, v.y, v.z, v.w};
            ushort4 h, l;
            unsigned short* hp = &h.x;
            unsigned short* lp = &l.x;
#pragma unroll
            for (int t = 0; t < 4; ++t) {
                s = fmaf(e[t], e[t], s);
                unsigned short hb = f2bf(e[t]);
                hp[t] = hb;
                lp[t] = f2bf(e[t] - bf2f(hb));
            }
            *reinterpret_cast<ushort4*>(&cb_hi[(size_t)j * LAT_N + lq * 4]) = h;
            *reinterpret_cast<ushort4*>(&cb_lo[(size_t)j * LAT_N + lq * 4]) = l;
        }
        cn[j] = s;
    }
}

// VQ scores via bf16x3 MFMA with top-2 tracking (pre-split z).
__global__ __launch_bounds__(256) void vq_mfma(
    const unsigned short* __restrict__ zhi, const unsigned short* __restrict__ zlo,
    const unsigned short* __restrict__ cb_hi,
    const unsigned short* __restrict__ cb_lo, const float* __restrict__ cnorm,
    float4* __restrict__ cand)
{
    const int lane = threadIdx.x & 63;
    const int wid  = blockIdx.x * 4 + (threadIdx.x >> 6);
    const int rbase = (wid >> 3) * 64;
    const int cblk  = wid & 7;
    const int cbase = cblk * 256;
    const int lr = lane & 15;
    const int lg = lane >> 4;

    s8v a_hi[4][2], a_lo[4][2];
#pragma unroll
    for (int rt = 0; rt < 4; ++rt) {
        int row = rbase + rt * 16 + lr;
#pragma unroll
        for (int ks = 0; ks < 2; ++ks) {
            size_t off = (size_t)row * LAT_N + ks * 32 + lg * 8;
            a_hi[rt][ks] = *reinterpret_cast<const s8v*>(&zhi[off]);
            a_lo[rt][ks] = *reinterpret_cast<const s8v*>(&zlo[off]);
        }
    }

    float b1[4][4], b2[4][4];
    int j1[4][4];
#pragma unroll
    for (int rt = 0; rt < 4; ++rt)
#pragma unroll
        for (int i = 0; i < 4; ++i) {
            b1[rt][i] = 3.4e38f; b2[rt][i] = 3.4e38f; j1[rt][i] = 0;
        }

    for (int ct = 0; ct < 16; ++ct) {
        int col = cbase + ct * 16 + lr;
        const unsigned short* ph = &cb_hi[(size_t)col * LAT_N + lg * 8];
        const unsigned short* pl = &cb_lo[(size_t)col * LAT_N + lg * 8];
        s8v bh0 = *reinterpret_cast<const s8v*>(ph);
        s8v bh1 = *reinterpret_cast<const s8v*>(ph + 32);
        s8v bl0 = *reinterpret_cast<const s8v*>(pl);
        s8v bl1 = *reinterpret_cast<const s8v*>(pl + 32);
        float cn = cnorm[col];
#pragma unroll
        for (int rt = 0; rt < 4; ++rt) {
            f4v acc = {0.f, 0.f, 0.f, 0.f};
            acc = __builtin_amdgcn_mfma_f32_16x16x32_bf16(a_hi[rt][0], bh0, acc, 0, 0, 0);
            acc = __builtin_amdgcn_mfma_f32_16x16x32_bf16(a_hi[rt][1], bh1, acc, 0, 0, 0);
            acc = __builtin_amdgcn_mfma_f32_16x16x32_bf16(a_lo[rt][0], bh0, acc, 0, 0, 0);
            acc = __builtin_amdgcn_mfma_f32_16x16x32_bf16(a_lo[rt][1], bh1, acc, 0, 0, 0);
            acc = __builtin_amdgcn_mfma_f32_16x16x32_bf16(a_hi[rt][0], bl0, acc, 0, 0, 0);
            acc = __builtin_amdgcn_mfma_f32_16x16x32_bf16(a_hi[rt][1], bl1, acc, 0, 0, 0);
#pragma unroll
            for (int i = 0; i < 4; ++i) {
                float d = fmaf(-2.f, acc[i], cn);
                if (d < b1[rt][i]) {
                    b2[rt][i] = b1[rt][i];
                    b1[rt][i] = d;
                    j1[rt][i] = col;
                } else if (d < b2[rt][i]) {
                    b2[rt][i] = d;
                }
            }
        }
    }

#pragma unroll
    for (int off = 1; off < 16; off <<= 1) {
#pragma unroll
        for (int rt = 0; rt < 4; ++rt)
#pragma unroll
            for (int i = 0; i < 4; ++i) {
                float o1 = __shfl_xor(b1[rt][i], off);
                float o2 = __shfl_xor(b2[rt][i], off);
                int oj = __shfl_xor(j1[rt][i], off);
                float nb2 = fminf(fmaxf(b1[rt][i], o1), fminf(b2[rt][i], o2));
                if (o1 < b1[rt][i] ||
                    (o1 == b1[rt][i] && oj < j1[rt][i])) {
                    b1[rt][i] = o1;
                    j1[rt][i] = oj;
                }
                b2[rt][i] = nb2;
            }
    }
    if (lr == 0) {
#pragma unroll
        for (int rt = 0; rt < 4; ++rt)
#pragma unroll
            for (int i = 0; i < 4; ++i) {
                int row = rbase + rt * 16 + lg * 4 + i;
                cand[(size_t)row * 8 + cblk] = make_float4(
                    b1[rt][i], __int_as_float(j1[rt][i]), b2[rt][i], 0.f);
            }
    }
}

// merge 8 col-block candidates/row; unflagged: gather z_q + loss here.
__global__ __launch_bounds__(256) void vq_merge(
    const float4* __restrict__ cand, const float* __restrict__ z,
    const float* __restrict__ cb,
    const unsigned short* __restrict__ cbhi,
    const unsigned short* __restrict__ cblo,
    unsigned short* __restrict__ zqhi, unsigned short* __restrict__ zqlo,
    float* __restrict__ idxf,
    int* __restrict__ rlist, int* __restrict__ rcnt,
    float* __restrict__ mergep)
{
    __shared__ float red[256];
    int tid = threadIdx.x;
    int row = blockIdx.x * 256 + tid;
    const float4* c = &cand[(size_t)row * 8];
    float4 c0 = c[0];
    float b1 = c0.x, b2 = c0.z;
    int j1 = __float_as_int(c0.y);
#pragma unroll
    for (int t = 1; t < 8; ++t) {
        float4 ct = c[t];
        float o1 = ct.x, o2 = ct.z;
        int oj = __float_as_int(ct.y);
        float nb2 = fminf(fmaxf(b1, o1), fminf(b2, o2));
        if (o1 < b1 || (o1 == b1 && oj < j1)) { b1 = o1; j1 = oj; }
        b2 = nb2;
    }
    idxf[row] = (float)j1;
    float sq = 0.f;
    if (b2 - b1 >= VQ_MARGIN) {
#pragma unroll
        for (int lq = 0; lq < 16; ++lq) {
            float4 cv = *reinterpret_cast<const float4*>(&cb[(size_t)j1 * LAT_N + lq * 4]);
            float4 zv = *reinterpret_cast<const float4*>(&z[(size_t)row * LAT_N + lq * 4]);
            float d0 = cv.x - zv.x, d1 = cv.y - zv.y;
            float d2 = cv.z - zv.z, d3 = cv.w - zv.w;
            sq = fmaf(d0, d0, sq); sq = fmaf(d1, d1, sq);
            sq = fmaf(d2, d2, sq); sq = fmaf(d3, d3, sq);
        }
        const uint4* gh = reinterpret_cast<const uint4*>(&cbhi[(size_t)j1 * LAT_N]);
        const uint4* gl = reinterpret_cast<const uint4*>(&cblo[(size_t)j1 * LAT_N]);
        uint4* dh = reinterpret_cast<uint4*>(&zqhi[(size_t)row * LAT_N]);
        uint4* dl = reinterpret_cast<uint4*>(&zqlo[(size_t)row * LAT_N]);
#pragma unroll
        for (int q = 0; q < 8; ++q) { dh[q] = gh[q]; dl[q] = gl[q]; }
    } else {
        int s = atomicAdd(rcnt, 1);
        if (s < B_ROWS) rlist[s] = row;
    }
    red[tid] = sq;
    __syncthreads();
    for (int off = 128; off > 0; off >>= 1) {
        if (tid < off) red[tid] += red[tid + off];
        __syncthreads();
    }
    if (tid == 0) mergep[blockIdx.x] = red[0];
}

// flagged rows: exact-f32 scan over compact zr; writes idx, z_q, loss.
#define RB 8
__global__ __launch_bounds__(256) void repair_scan(
    const int* __restrict__ rcnt, const int* __restrict__ rlist,
    const float* __restrict__ zr,
    const float* __restrict__ cb, const float* __restrict__ cn,
    const unsigned short* __restrict__ cbhi,
    const unsigned short* __restrict__ cblo,
    unsigned short* __restrict__ zqhi, unsigned short* __restrict__ zqlo,
    float* __restrict__ idxf, float* __restrict__ repairp)
{
    __shared__ float sz[RB][LAT_N];
    __shared__ float rv[256];
    __shared__ int ri[256];
    const int tid = threadIdx.x;
    const int count = min(rcnt[0], B_ROWS);
    if (blockIdx.x * RB >= count) return;
    float lsum = 0.f;
    for (int base = blockIdx.x * RB; base < count; base += gridDim.x * RB) {
        int nr = min(RB, count - base);
        __syncthreads();
        for (int s = tid; s < nr * LAT_N; s += 256) {
            int r = s >> 6, d = s & 63;
            sz[r][d] = zr[(size_t)(base + r) * LAT_N + d];
        }
        __syncthreads();
        float bv[RB];
        int bj[RB];
#pragma unroll
        for (int r = 0; r < RB; ++r) { bv[r] = 3.4e38f; bj[r] = 0; }
        for (int k = 0; k < K_CB / 256; ++k) {
            int cidx = tid + k * 256;
            float a[RB];
#pragma unroll
            for (int r = 0; r < RB; ++r) a[r] = 0.f;
            const float* cp = &cb[(size_t)cidx * LAT_N];
#pragma unroll 2
            for (int d4 = 0; d4 < 16; ++d4) {
                float4 cv = *reinterpret_cast<const float4*>(cp + d4 * 4);
#pragma unroll
                for (int r = 0; r < RB; ++r) {
                    a[r] = fmaf(sz[r][d4 * 4 + 0], cv.x, a[r]);
                    a[r] = fmaf(sz[r][d4 * 4 + 1], cv.y, a[r]);
                    a[r] = fmaf(sz[r][d4 * 4 + 2], cv.z, a[r]);
                    a[r] = fmaf(sz[r][d4 * 4 + 3], cv.w, a[r]);
                }
            }
            float cnv = cn[cidx];
#pragma unroll
            for (int r = 0; r < RB; ++r) {
                float d = fmaf(-2.f, a[r], cnv);
                if (d < bv[r] || (d == bv[r] && cidx < bj[r])) {
                    bv[r] = d; bj[r] = cidx;
                }
            }
        }
        for (int r = 0; r < RB; ++r) {
            if (r >= nr) break;
            rv[tid] = bv[r];
            ri[tid] = bj[r];
            __syncthreads();
            for (int off = 128; off > 0; off >>= 1) {
                if (tid < off) {
                    float ov = rv[tid + off];
                    int oi = ri[tid + off];
                    if (ov < rv[tid] || (ov == rv[tid] && oi < ri[tid])) {
                        rv[tid] = ov; ri[tid] = oi;
                    }
                }
                __syncthreads();
            }
            int bjf = ri[0];
            int rr = rlist[base + r];
            bool ok = (unsigned)rr < (unsigned)B_ROWS;
            rr = ok ? rr : 0;
            if (tid == 0 && ok) idxf[rr] = (float)bjf;
            float v = 0.f;
            if (tid < 64) {
                float d = cb[(size_t)bjf * LAT_N + tid] - sz[r][tid];
                v = d * d;
            }
            __syncthreads();
            rv[tid] = v;
            __syncthreads();
            for (int off = 128; off > 0; off >>= 1) {
                if (tid < off) rv[tid] += rv[tid + off];
                __syncthreads();
            }
            if (tid == 0) lsum += rv[0];
            if (ok) {
                if (tid < 8)
                    reinterpret_cast<uint4*>(&zqhi[(size_t)rr * LAT_N])[tid] =
                        reinterpret_cast<const uint4*>(&cbhi[(size_t)bjf * LAT_N])[tid];
                else if (tid < 16)
                    reinterpret_cast<uint4*>(&zqlo[(size_t)rr * LAT_N])[tid - 8] =
                        reinterpret_cast<const uint4*>(&cblo[(size_t)bjf * LAT_N])[tid - 8];
            }
            __syncthreads();
        }
    }
    if (tid == 0) repairp[blockIdx.x] = lsum;
}

__global__ __launch_bounds__(256) void finalize_kernel(
    const float* __restrict__ mergep, int nm,
    const float* __restrict__ repairp, int nr,
    const float* __restrict__ rep, int nre,
    float* __restrict__ vq_out, float* __restrict__ re_out)
{
    __shared__ float s[256];
    int tid = threadIdx.x;
    float a = 0.f;
    for (int i = tid; i < nm; i += 256) a += mergep[i];
    for (int i = tid; i < nr; i += 256) a += repairp[i];
    s[tid] = a;
    __syncthreads();
    for (int off = 128; off > 0; off >>= 1) {
        if (tid < off) s[tid] += s[tid + off];
        __syncthreads();
    }
    if (tid == 0) *vq_out = 1.25f * s[0] / (float)(B_ROWS * LAT_N);
    __syncthreads();
    float b = 0.f;
    for (int i = tid; i < nre; i += 256) b += rep[i];
    s[tid] = b;
    __syncthreads();
    for (int off = 128; off > 0; off >>= 1) {
        if (tid < off) s[tid] += s[tid + off];
        __syncthreads();
    }
    if (tid == 0) *re_out = s[0] / (float)(B_ROWS * D_IN);
}

extern "C" void kernel_launch(void* const* d_in, const int* in_sizes, int n_in,
                              void* d_out, int out_size, void* d_ws, size_t ws_size,
                              hipStream_t stream)
{
    const float* x    = (const float*)d_in[0];
    const float* ew1  = (const float*)d_in[1];
    const float* eb1  = (const float*)d_in[2];
    const float* eg1  = (const float*)d_in[3];
    const float* ebt1 = (const float*)d_in[4];
    const float* em1  = (const float*)d_in[5];
    const float* ev1  = (const float*)d_in[6];
    const float* ew2  = (const float*)d_in[7];
    const float* eb2  = (const float*)d_in[8];
    const float* eg2  = (const float*)d_in[9];
    const float* ebt2 = (const float*)d_in[10];
    const float* em2  = (const float*)d_in[11];
    const float* ev2  = (const float*)d_in[12];
    const float* ew3  = (const float*)d_in[13];
    const float* eb3  = (const float*)d_in[14];
    const float* cb   = (const float*)d_in[15];
    const float* dw1  = (const float*)d_in[16];
    const float* db1  = (const float*)d_in[17];
    const float* dg1  = (const float*)d_in[18];
    const float* dbt1 = (const float*)d_in[19];
    const float* dm1  = (const float*)d_in[20];
    const float* dv1  = (const float*)d_in[21];
    const float* dw2  = (const float*)d_in[22];
    const float* db2  = (const float*)d_in[23];
    const float* dg2  = (const float*)d_in[24];
    const float* dbt2 = (const float*)d_in[25];
    const float* dm2  = (const float*)d_in[26];
    const float* dv2  = (const float*)d_in[27];
    const float* dw3  = (const float*)d_in[28];
    const float* db3  = (const float*)d_in[29];

    float* outf = (float*)d_out;
    const size_t XR_OFF = 0;
    const size_t VQ_OFF = (size_t)B_ROWS * D_IN;
    const size_t IDX_OFF = VQ_OFF + 1;
    const size_t RE_OFF = IDX_OFF + B_ROWS;

    float* wsf = (float*)d_ws;
    size_t off = 0;
    float* buf256 = wsf + off; off += (size_t)B_ROWS * H1_N;
    float* buf128 = wsf + off; off += (size_t)B_ROWS * H2_N;
    float* zbuf   = wsf + off; off += (size_t)B_ROWS * LAT_N;
    float* zr     = wsf + off; off += (size_t)B_ROWS * LAT_N;
    float* cnbuf  = wsf + off; off += K_CB;
    float* mergep = wsf + off; off += 128;
    float* repairp= wsf + off; off += 256;
    float* rep    = wsf + off; off += 2048;
    unsigned short* cbhi = (unsigned short*)(wsf + off); off += K_CB * LAT_N / 2;
    unsigned short* cblo = (unsigned short*)(wsf + off); off += K_CB * LAT_N / 2;
    float4* candb = (float4*)(wsf + off); off += (size_t)B_ROWS * 8 * 4;
    int* rcnt  = (int*)(wsf + off); off += 16;
    int* rlist = (int*)(wsf + off); off += B_ROWS;
    unsigned short* w1hi = (unsigned short*)(wsf + off); off += (H2_N * LAT_N) / 2;
    unsigned short* w1lo = (unsigned short*)(wsf + off); off += (H2_N * LAT_N) / 2;
    unsigned short* w2hi = (unsigned short*)(wsf + off); off += (H1_N * H2_N) / 2;
    unsigned short* w2lo = (unsigned short*)(wsf + off); off += (H1_N * H2_N) / 2;
    unsigned short* w3hi = (unsigned short*)(wsf + off); off += (D_IN * H1_N) / 2;
    unsigned short* w3lo = (unsigned short*)(wsf + off); off += (D_IN * H1_N) / 2;
    unsigned short* e1hi = (unsigned short*)(wsf + off); off += (D_IN * H1_N) / 2;
    unsigned short* e1lo = (unsigned short*)(wsf + off); off += (D_IN * H1_N) / 2;
    unsigned short* e2hi = (unsigned short*)(wsf + off); off += (H1_N * H2_N) / 2;
    unsigned short* e2lo = (unsigned short*)(wsf + off); off += (H1_N * H2_N) / 2;
    unsigned short* e3hi = (unsigned short*)(wsf + off); off += (H2_N * LAT_N) / 2;
    unsigned short* e3lo = (unsigned short*)(wsf + off); off += (H2_N * LAT_N) / 2;
    unsigned short* zqhi = (unsigned short*)(wsf + off); off += (size_t)B_ROWS * LAT_N / 2;
    unsigned short* zqlo = (unsigned short*)(wsf + off); off += (size_t)B_ROWS * LAT_N / 2;

    // time-disjoint aliases:
    unsigned short* eh1hi = (unsigned short*)buf256;
    unsigned short* eh1lo = (unsigned short*)(buf256 + (size_t)B_ROWS * 128);
    unsigned short* zhi   = (unsigned short*)buf256;
    unsigned short* zlo   = (unsigned short*)(buf256 + (size_t)B_ROWS * 32);
    float*          h1r   = buf256;
    unsigned short* dh2hi = (unsigned short*)buf256;
    unsigned short* dh2lo = (unsigned short*)(buf256 + (size_t)B_ROWS * 128);
    unsigned short* eh2hi = (unsigned short*)buf128;
    unsigned short* eh2lo = (unsigned short*)(buf128 + (size_t)B_ROWS * 64);
    float*          h2r   = buf128;
    unsigned short* dh1hi = (unsigned short*)buf128;
    unsigned short* dh1lo = (unsigned short*)(buf128 + (size_t)B_ROWS * 64);

    dim3 blk(256);
    const int GM64 = B_ROWS / 64;    // 512

    prep_all<<<dim3(1352), blk, 0, stream>>>(
        dw3, w3hi, w3lo, dw2, w2hi, w2lo, dw1, w1hi, w1lo,
        ew1, e1hi, e1lo, ew2, e2hi, e2lo, ew3, e3hi, e3lo,
        cb, cbhi, cblo, cnbuf, rcnt, repairp);

    // encoder (bf16x3 MFMA, 64-row tiles, double-buffered K loop)
    mfma_gemm<0, D_IN, 2, 4, true><<<dim3(GM64, H1_N / 128), blk, 0, stream>>>(
        x, nullptr, nullptr, e1hi, e1lo, eb1, eg1, ebt1, em1, ev1,
        eh1hi, eh1lo, nullptr, nullptr, nullptr, H1_N);
    mfma_gemm<0, H1_N, 2, 2, false><<<dim3(GM64, H2_N / 64), blk, 0, stream>>>(
        nullptr, eh1hi, eh1lo, e2hi, e2lo, eb2, eg2, ebt2, em2, ev2,
        eh2hi, eh2lo, nullptr, nullptr, nullptr, H2_N);
    mfma_gemm<3, H2_N, 2, 2, false><<<dim3(GM64, 1), blk, 0, stream>>>(
        nullptr, eh2hi, eh2lo, e3hi, e3lo, eb3, nullptr, nullptr, nullptr, nullptr,
        zhi, zlo, zbuf, nullptr, nullptr, LAT_N);

    // vector quantization
    vq_mfma<<<dim3(1024), blk, 0, stream>>>(zhi, zlo, cbhi, cblo, cnbuf, candb);
    vq_merge<<<dim3(B_ROWS / 256), blk, 0, stream>>>(
        candb, zbuf, cb, cbhi, cblo, zqhi, zqlo,
        outf + IDX_OFF, rlist, rcnt, mergep);

    // repair: exact f32 encoder on flagged rows + exact scan
    rgemm<0, true><<<dim3(GM64, 2), blk, 0, stream>>>(
        rcnt, rlist, x, ew1, eb1, eg1, ebt1, em1, ev1, h1r, D_IN, H1_N);
    rgemm<0, false><<<dim3(GM64, 1), blk, 0, stream>>>(
        rcnt, rlist, h1r, ew2, eb2, eg2, ebt2, em2, ev2, h2r, H1_N, H2_N);
    rgemm<1, false><<<dim3(GM64, 1), blk, 0, stream>>>(
        rcnt, rlist, h2r, ew3, eb3, nullptr, nullptr, nullptr, nullptr,
        zr, H2_N, LAT_N);
    repair_scan<<<dim3(256), blk, 0, stream>>>(
        rcnt, rlist, zr, cb, cnbuf, cbhi, cblo, zqhi, zqlo,
        outf + IDX_OFF, repairp);

    // decoder (bf16x3 MFMA, 64-row tiles)
    mfma_gemm<0, LAT_N, 2, 2, false><<<dim3(GM64, H2_N / 64), blk, 0, stream>>>(
        nullptr, zqhi, zqlo, w1hi, w1lo, db1, dg1, dbt1, dm1, dv1,
        dh1hi, dh1lo, nullptr, nullptr, nullptr, H2_N);
    mfma_gemm<0, H2_N, 2, 4, false><<<dim3(GM64, H1_N / 128), blk, 0, stream>>>(
        nullptr, dh1hi, dh1lo, w2hi, w2lo, db2, dg2, dbt2, dm2, dv2,
        dh2hi, dh2lo, nullptr, nullptr, nullptr, H1_N);
    mfma_gemm<2, H1_N, 2, 4, false><<<dim3(GM64, D_IN / 128), blk, 0, stream>>>(
        nullptr, dh2hi, dh2lo, w3hi, w3lo, db3, nullptr, nullptr, nullptr, nullptr,
        nullptr, nullptr, outf + XR_OFF, x, rep, D_IN);

    finalize_kernel<<<dim3(1), blk, 0, stream>>>(
        mergep, 128, repairp, 256, rep, 2048, outf + VQ_OFF, outf + RE_OFF);
}

// Round 12
// 434.742 us; speedup vs baseline: 1.2235x; 1.2235x over previous
//
#include <hip/hip_runtime.h>

#define B_ROWS 32768
#define D_IN   512
#define H1_N   256
#define H2_N   128
#define LAT_N  64
#define K_CB   2048

#define VQ_MARGIN 6.0e-3f
#define BK 32
#define BN 128

typedef __attribute__((ext_vector_type(8))) short s8v;   // 8 bf16 (4 VGPRs)
typedef __attribute__((ext_vector_type(4))) float f4v;   // 4 f32 acc

__device__ inline unsigned short f2bf(float f) {
    union { float f; unsigned u; } v; v.f = f;
    unsigned r = v.u + 0x7fffu + ((v.u >> 16) & 1u);
    return (unsigned short)(r >> 16);
}
__device__ inline float bf2f(unsigned short h) {
    union { unsigned u; float f; } v; v.u = ((unsigned)h) << 16;
    return v.f;
}

// fragment-packed layout: tile (r/16, k/32) is 512 contiguous elems (1KB);
// within tile: [(k/8)%4][r%16][k%8]  -> fragment load = wave-contiguous 1KB
__device__ inline int pidx(int r, int k, int K) {
    return ((r >> 4) * (K >> 5) + (k >> 5)) * 512 + (((k >> 3) & 3) << 7)
         + ((r & 15) << 3) + (k & 7);
}

// XOR swizzle for k-major LDS A-tiles (f32 repair GEMM)
#define SWZ(row) ((((row) >> 2) & 7) << 3)

// ---------------- universal MFMA GEMM (bf16x3, packed operands) ----------
// 256 thr = 2x2 waves; block tile 128 x (32*CT).
// MODE 0: v = BN(ReLU(A@W+b)) -> packed out_hi/out_lo
// MODE 2: v = A@W+b -> out_f32 (row-major), + (v-xref)^2 partials
// MODE 3: v = A@W+b -> out_f32 AND packed out_hi/out_lo
template <int MODE, int K, int CT, bool ASPLIT>
__global__ __launch_bounds__(256, 2) void mfma_gemm(
    const float* __restrict__ A_f32,
    const unsigned short* __restrict__ A_hi,
    const unsigned short* __restrict__ A_lo,
    const unsigned short* __restrict__ w_hi,
    const unsigned short* __restrict__ w_lo,
    const float* __restrict__ bias,
    const float* __restrict__ bn_g, const float* __restrict__ bn_b,
    const float* __restrict__ bn_m, const float* __restrict__ bn_v,
    unsigned short* __restrict__ out_hi, unsigned short* __restrict__ out_lo,
    float* __restrict__ out_f32,
    const float* __restrict__ xref, float* __restrict__ partials, int N)
{
    const int lane = threadIdx.x & 63;
    const int wv = threadIdx.x >> 6;
    const int wr = wv >> 1, wc = wv & 1;
    const int rbase = blockIdx.x * 128 + wr * 64;
    const int cbase = blockIdx.y * (32 * CT) + wc * (16 * CT);
    const int lr = lane & 15, lg = lane >> 4;

    f4v acc[4][CT];
#pragma unroll
    for (int rt = 0; rt < 4; ++rt)
#pragma unroll
        for (int ct = 0; ct < CT; ++ct)
            acc[rt][ct] = (f4v){0.f, 0.f, 0.f, 0.f};

    for (int ks = 0; ks < K / 32; ++ks) {
        s8v ah[4], al[4], bh[CT], bl[CT];
#pragma unroll
        for (int rt = 0; rt < 4; ++rt) {
            if constexpr (ASPLIT) {
                size_t aoff = (size_t)(rbase + rt * 16 + lr) * K + ks * 32 + lg * 8;
                const float* p = &A_f32[aoff];
                float4 v0 = *reinterpret_cast<const float4*>(p);
                float4 v1 = *reinterpret_cast<const float4*>(p + 4);
                float fv[8] = {v0.x, v0.y, v0.z, v0.w, v1.x, v1.y, v1.z, v1.w};
                unsigned uu[8], llv[8];
#pragma unroll
                for (int j = 0; j < 8; ++j) {
                    uu[j] = __float_as_uint(fv[j]);
                    float lo = fv[j] - __uint_as_float(uu[j] & 0xffff0000u);
                    llv[j] = __float_as_uint(lo);
                }
                union { s8v v; unsigned w[4]; } H, L;
#pragma unroll
                for (int m = 0; m < 4; ++m) {
                    H.w[m] = __builtin_amdgcn_perm(uu[2 * m + 1], uu[2 * m], 0x07060302u);
                    L.w[m] = __builtin_amdgcn_perm(llv[2 * m + 1], llv[2 * m], 0x07060302u);
                }
                ah[rt] = H.v;
                al[rt] = L.v;
            } else {
                // packed: tile ((rbase>>4)+rt, ks) + lg*128 + lr*8 (contiguous)
                int off = (((rbase >> 4) + rt) * (K >> 5) + ks) * 512 + lg * 128 + lr * 8;
                ah[rt] = *reinterpret_cast<const s8v*>(&A_hi[off]);
                al[rt] = *reinterpret_cast<const s8v*>(&A_lo[off]);
            }
        }
#pragma unroll
        for (int ct = 0; ct < CT; ++ct) {
            int off = (((cbase >> 4) + ct) * (K >> 5) + ks) * 512 + lg * 128 + lr * 8;
            bh[ct] = *reinterpret_cast<const s8v*>(&w_hi[off]);
            bl[ct] = *reinterpret_cast<const s8v*>(&w_lo[off]);
        }
#pragma unroll
        for (int rt = 0; rt < 4; ++rt)
#pragma unroll
            for (int ct = 0; ct < CT; ++ct) {
                acc[rt][ct] = __builtin_amdgcn_mfma_f32_16x16x32_bf16(
                    ah[rt], bh[ct], acc[rt][ct], 0, 0, 0);
                acc[rt][ct] = __builtin_amdgcn_mfma_f32_16x16x32_bf16(
                    al[rt], bh[ct], acc[rt][ct], 0, 0, 0);
                acc[rt][ct] = __builtin_amdgcn_mfma_f32_16x16x32_bf16(
                    ah[rt], bl[ct], acc[rt][ct], 0, 0, 0);
            }
    }

    float sq = 0.f;
#pragma unroll
    for (int ct = 0; ct < CT; ++ct) {
        int col = cbase + ct * 16 + lr;
        float bi = bias[col];
        float sc = 0.f, sh = 0.f;
        if (MODE == 0) {
            float s = bn_g[col] * rsqrtf(bn_v[col] + 1e-5f);
            sc = s;
            sh = bn_b[col] - bn_m[col] * s;
        }
#pragma unroll
        for (int rt = 0; rt < 4; ++rt)
#pragma unroll
            for (int i = 0; i < 4; ++i) {
                int row = rbase + rt * 16 + lg * 4 + i;
                float v = acc[rt][ct][i] + bi;
                if (MODE == 0) v = fmaxf(v, 0.f) * sc + sh;
                if (MODE == 0 || MODE == 3) {
                    unsigned u = __float_as_uint(v);
                    int p = pidx(row, col, N);
                    out_hi[p] = (unsigned short)(u >> 16);
                    out_lo[p] = f2bf(v - __uint_as_float(u & 0xffff0000u));
                }
                if (MODE == 2) {
                    float d = v - xref[(size_t)row * N + col];
                    sq = fmaf(d, d, sq);
                }
                if (MODE == 2 || MODE == 3)
                    out_f32[(size_t)row * N + col] = v;
            }
    }
    if (MODE == 2) {
        __shared__ float red[256];
        red[threadIdx.x] = sq;
        __syncthreads();
        for (int off = 128; off > 0; off >>= 1) {
            if (threadIdx.x < off) red[threadIdx.x] += red[threadIdx.x + off];
            __syncthreads();
        }
        if (threadIdx.x == 0)
            partials[blockIdx.y * gridDim.x + blockIdx.x] = red[0];
    }
}

// ---- f32 GEMM for flagged-row repair (64x128 tile, dynamic M, gather) ---
template <int MODE, bool GATHER>
__global__ __launch_bounds__(256, 6) void rgemm(
    const int* __restrict__ rcnt, const int* __restrict__ rlist,
    const float* __restrict__ A, const float* __restrict__ W,
    const float* __restrict__ bias,
    const float* __restrict__ bn_g, const float* __restrict__ bn_b,
    const float* __restrict__ bn_m, const float* __restrict__ bn_v,
    float* __restrict__ out, int M, int N)
{
    const int count = min(rcnt[0], B_ROWS);
    const int row0 = blockIdx.x * 64;
    if (row0 >= count) return;
    __shared__ float sA[BK][64];
    __shared__ float sB[BK][BN];
    const int tid = threadIdx.x;
    const int tr = tid >> 4;
    const int tc = tid & 15;
    const int n0 = blockIdx.y * BN;

    float acc[4][8];
#pragma unroll
    for (int i = 0; i < 4; ++i)
#pragma unroll
        for (int j = 0; j < 8; ++j) acc[i][j] = 0.f;

    for (int k0 = 0; k0 < M; k0 += BK) {
#pragma unroll
        for (int it = 0; it < 2; ++it) {
            int s = tid + it * 256;
            int m = s >> 3;
            int kq = s & 7;
            int i = row0 + m;
            int src;
            if (GATHER) {
                int rr = (i < count) ? rlist[i] : 0;
                src = ((unsigned)rr < (unsigned)B_ROWS) ? rr : 0;
            } else {
                src = i;
            }
            float4 v = *reinterpret_cast<const float4*>(
                &A[(size_t)src * M + k0 + kq * 4]);
            int kk = kq * 4;
            sA[kk + 0][m ^ SWZ(kk + 0)] = v.x;
            sA[kk + 1][m ^ SWZ(kk + 1)] = v.y;
            sA[kk + 2][m ^ SWZ(kk + 2)] = v.z;
            sA[kk + 3][m ^ SWZ(kk + 3)] = v.w;
        }
#pragma unroll
        for (int it = 0; it < 4; ++it) {
            int s = tid + it * 256;
            int k = s >> 5;
            int nq = s & 31;
            int n = n0 + nq * 4;
            float4 v = make_float4(0.f, 0.f, 0.f, 0.f);
            if (n < N)
                v = *reinterpret_cast<const float4*>(&W[(size_t)(k0 + k) * N + n]);
            *reinterpret_cast<float4*>(&sB[k][nq * 4]) = v;
        }
        __syncthreads();
#pragma unroll 4
        for (int k = 0; k < BK; ++k) {
            int ac = (tr * 4) ^ SWZ(k);
            float4 a0 = *reinterpret_cast<float4*>(&sA[k][ac]);
            float a[4] = {a0.x, a0.y, a0.z, a0.w};
            float4 b0 = *reinterpret_cast<float4*>(&sB[k][tc * 4]);
            float4 b1 = *reinterpret_cast<float4*>(&sB[k][64 + tc * 4]);
            float b[8] = {b0.x, b0.y, b0.z, b0.w, b1.x, b1.y, b1.z, b1.w};
#pragma unroll
            for (int i = 0; i < 4; ++i)
#pragma unroll
                for (int j = 0; j < 8; ++j)
                    acc[i][j] = fmaf(a[i], b[j], acc[i][j]);
        }
        __syncthreads();
    }

    const int nb0 = n0 + tc * 4;
    const int nb1 = n0 + 64 + tc * 4;
    float bi[8], sc[8], sh[8];
#pragma unroll
    for (int g = 0; g < 2; ++g) {
        int nb = g ? nb1 : nb0;
        if (nb < N) {
#pragma unroll
            for (int j = 0; j < 4; ++j) {
                int n = nb + j;
                bi[g * 4 + j] = bias[n];
                if (MODE == 0) {
                    float s = bn_g[n] * rsqrtf(bn_v[n] + 1e-5f);
                    sc[g * 4 + j] = s;
                    sh[g * 4 + j] = bn_b[n] - bn_m[n] * s;
                }
            }
        }
    }
#pragma unroll
    for (int i = 0; i < 4; ++i) {
        int row = row0 + tr * 4 + i;
#pragma unroll
        for (int g = 0; g < 2; ++g) {
            int nb = g ? nb1 : nb0;
            if (nb < N) {
                float o[4];
#pragma unroll
                for (int j = 0; j < 4; ++j) {
                    float v = acc[i][g * 4 + j] + bi[g * 4 + j];
                    if (MODE == 0) {
                        v = v > 0.f ? v : 0.f;
                        v = v * sc[g * 4 + j] + sh[g * 4 + j];
                    }
                    o[j] = v;
                }
                *reinterpret_cast<float4*>(&out[(size_t)row * N + nb]) =
                    make_float4(o[0], o[1], o[2], o[3]);
            }
        }
    }
}

// ---------------- fused prep: packed weight splits + codebook ------------
__device__ inline void wprep_packed(const float* __restrict__ w,
                                    unsigned short* __restrict__ w_hi,
                                    unsigned short* __restrict__ w_lo,
                                    int K, int N, int t)
{
    // t in [0, N*K/8): operand-row n, 8 consecutive k
    if (t >= N * (K >> 3)) return;
    int n = t / (K >> 3);
    int k0 = (t - n * (K >> 3)) << 3;
    union { unsigned short s[8]; uint4 v; } H, L;
#pragma unroll
    for (int j = 0; j < 8; ++j) {
        float f = w[(size_t)(k0 + j) * N + n];
        unsigned u = __float_as_uint(f);
        float lo = f - __uint_as_float(u & 0xffff0000u);
        H.s[j] = (unsigned short)(u >> 16);
        L.s[j] = f2bf(lo);
    }
    int p = pidx(n, k0, K);
    *reinterpret_cast<uint4*>(&w_hi[p]) = H.v;
    *reinterpret_cast<uint4*>(&w_lo[p]) = L.v;
}

__global__ __launch_bounds__(256) void prep_all(
    const float* __restrict__ dw3, unsigned short* w3hi, unsigned short* w3lo,
    const float* __restrict__ dw2, unsigned short* w2hi, unsigned short* w2lo,
    const float* __restrict__ dw1, unsigned short* w1hi, unsigned short* w1lo,
    const float* __restrict__ ew1, unsigned short* e1hi, unsigned short* e1lo,
    const float* __restrict__ ew2, unsigned short* e2hi, unsigned short* e2lo,
    const float* __restrict__ ew3, unsigned short* e3hi, unsigned short* e3lo,
    const float* __restrict__ cb, unsigned short* cb_hi, unsigned short* cb_lo,
    float* __restrict__ cn, int* __restrict__ rcnt, float* __restrict__ repairp)
{
    int bid = blockIdx.x;
    int tid = threadIdx.x;
    if (bid < 64) {                        // dec w3: K=H1, N(out-rows)=D_IN
        wprep_packed(dw3, w3hi, w3lo, H1_N, D_IN, bid * 256 + tid);
    } else if (bid < 80) {                 // dec w2: K=H2, N=H1
        wprep_packed(dw2, w2hi, w2lo, H2_N, H1_N, (bid - 64) * 256 + tid);
    } else if (bid < 84) {                 // dec w1: K=LAT, N=H2
        wprep_packed(dw1, w1hi, w1lo, LAT_N, H2_N, (bid - 80) * 256 + tid);
    } else if (bid < 148) {                // enc w1: K=D_IN, N=H1
        wprep_packed(ew1, e1hi, e1lo, D_IN, H1_N, (bid - 84) * 256 + tid);
    } else if (bid < 164) {                // enc w2: K=H1, N=H2
        wprep_packed(ew2, e2hi, e2lo, H1_N, H2_N, (bid - 148) * 256 + tid);
    } else if (bid < 168) {                // enc w3: K=H2, N=LAT
        wprep_packed(ew3, e3hi, e3lo, H2_N, LAT_N, (bid - 164) * 256 + tid);
    } else {                               // codebook: packed split + norms
        int blk = bid - 168;               // 0..7
        if (blk == 0) {
            if (tid == 0) rcnt[0] = 0;
            repairp[tid] = 0.f;
        }
        int j = blk * 256 + tid;
        float s = 0.f;
#pragma unroll
        for (int g = 0; g < 8; ++g) {
            float4 v0 = *reinterpret_cast<const float4*>(&cb[(size_t)j * LAT_N + g * 8]);
            float4 v1 = *reinterpret_cast<const float4*>(&cb[(size_t)j * LAT_N + g * 8 + 4]);
            float e[8] = {v0.x, v0.y, v0.z, v0.w, v1.x, v1.y, v1.z, v1.w};
            union { unsigned short us[8]; uint4 v; } H, L;
#pragma unroll
            for (int t = 0; t < 8; ++t) {
                s = fmaf(e[t], e[t], s);
                unsigned short hb = f2bf(e[t]);
                H.us[t] = hb;
                L.us[t] = f2bf(e[t] - bf2f(hb));
            }
            int p = pidx(j, g * 8, LAT_N);
            *reinterpret_cast<uint4*>(&cb_hi[p]) = H.v;
            *reinterpret_cast<uint4*>(&cb_lo[p]) = L.v;
        }
        cn[j] = s;
    }
}

// VQ scores via bf16x3 MFMA with top-2 tracking (packed z & codebook).
__global__ __launch_bounds__(256) void vq_mfma(
    const unsigned short* __restrict__ zhi, const unsigned short* __restrict__ zlo,
    const unsigned short* __restrict__ cb_hi,
    const unsigned short* __restrict__ cb_lo, const float* __restrict__ cnorm,
    float4* __restrict__ cand)
{
    const int lane = threadIdx.x & 63;
    const int wid  = blockIdx.x * 4 + (threadIdx.x >> 6);
    const int rbase = (wid >> 3) * 64;
    const int cblk  = wid & 7;
    const int cbase = cblk * 256;
    const int lr = lane & 15;
    const int lg = lane >> 4;

    s8v a_hi[4][2], a_lo[4][2];
#pragma unroll
    for (int rt = 0; rt < 4; ++rt) {
#pragma unroll
        for (int ks = 0; ks < 2; ++ks) {
            int off = (((rbase >> 4) + rt) * 2 + ks) * 512 + lg * 128 + lr * 8;
            a_hi[rt][ks] = *reinterpret_cast<const s8v*>(&zhi[off]);
            a_lo[rt][ks] = *reinterpret_cast<const s8v*>(&zlo[off]);
        }
    }

    float b1[4][4], b2[4][4];
    int j1[4][4];
#pragma unroll
    for (int rt = 0; rt < 4; ++rt)
#pragma unroll
        for (int i = 0; i < 4; ++i) {
            b1[rt][i] = 3.4e38f; b2[rt][i] = 3.4e38f; j1[rt][i] = 0;
        }

    for (int ct = 0; ct < 16; ++ct) {
        int col = cbase + ct * 16 + lr;
        int t0 = (((cbase >> 4) + ct) * 2 + 0) * 512 + lg * 128 + lr * 8;
        int t1 = t0 + 512;
        s8v bh0 = *reinterpret_cast<const s8v*>(&cb_hi[t0]);
        s8v bh1 = *reinterpret_cast<const s8v*>(&cb_hi[t1]);
        s8v bl0 = *reinterpret_cast<const s8v*>(&cb_lo[t0]);
        s8v bl1 = *reinterpret_cast<const s8v*>(&cb_lo[t1]);
        float cn = cnorm[col];
#pragma unroll
        for (int rt = 0; rt < 4; ++rt) {
            f4v acc = {0.f, 0.f, 0.f, 0.f};
            acc = __builtin_amdgcn_mfma_f32_16x16x32_bf16(a_hi[rt][0], bh0, acc, 0, 0, 0);
            acc = __builtin_amdgcn_mfma_f32_16x16x32_bf16(a_hi[rt][1], bh1, acc, 0, 0, 0);
            acc = __builtin_amdgcn_mfma_f32_16x16x32_bf16(a_lo[rt][0], bh0, acc, 0, 0, 0);
            acc = __builtin_amdgcn_mfma_f32_16x16x32_bf16(a_lo[rt][1], bh1, acc, 0, 0, 0);
            acc = __builtin_amdgcn_mfma_f32_16x16x32_bf16(a_hi[rt][0], bl0, acc, 0, 0, 0);
            acc = __builtin_amdgcn_mfma_f32_16x16x32_bf16(a_hi[rt][1], bl1, acc, 0, 0, 0);
#pragma unroll
            for (int i = 0; i < 4; ++i) {
                float d = fmaf(-2.f, acc[i], cn);
                if (d < b1[rt][i]) {
                    b2[rt][i] = b1[rt][i];
                    b1[rt][i] = d;
                    j1[rt][i] = col;
                } else if (d < b2[rt][i]) {
                    b2[rt][i] = d;
                }
            }
        }
    }

#pragma unroll
    for (int off = 1; off < 16; off <<= 1) {
#pragma unroll
        for (int rt = 0; rt < 4; ++rt)
#pragma unroll
            for (int i = 0; i < 4; ++i) {
                float o1 = __shfl_xor(b1[rt][i], off);
                float o2 = __shfl_xor(b2[rt][i], off);
                int oj = __shfl_xor(j1[rt][i], off);
                float nb2 = fminf(fmaxf(b1[rt][i], o1), fminf(b2[rt][i], o2));
                if (o1 < b1[rt][i] ||
                    (o1 == b1[rt][i] && oj < j1[rt][i])) {
                    b1[rt][i] = o1;
                    j1[rt][i] = oj;
                }
                b2[rt][i] = nb2;
            }
    }
    if (lr == 0) {
#pragma unroll
        for (int rt = 0; rt < 4; ++rt)
#pragma unroll
            for (int i = 0; i < 4; ++i) {
                int row = rbase + rt * 16 + lg * 4 + i;
                cand[(size_t)row * 8 + cblk] = make_float4(
                    b1[rt][i], __int_as_float(j1[rt][i]), b2[rt][i], 0.f);
            }
    }
}

// merge 8 col-block candidates/row; unflagged: gather packed z_q + loss.
__global__ __launch_bounds__(256) void vq_merge(
    const float4* __restrict__ cand, const float* __restrict__ z,
    const float* __restrict__ cb,
    const unsigned short* __restrict__ cbhi,
    const unsigned short* __restrict__ cblo,
    unsigned short* __restrict__ zqhi, unsigned short* __restrict__ zqlo,
    float* __restrict__ idxf,
    int* __restrict__ rlist, int* __restrict__ rcnt,
    float* __restrict__ mergep)
{
    __shared__ float red[256];
    int tid = threadIdx.x;
    int row = blockIdx.x * 256 + tid;
    const float4* c = &cand[(size_t)row * 8];
    float4 c0 = c[0];
    float b1 = c0.x, b2 = c0.z;
    int j1 = __float_as_int(c0.y);
#pragma unroll
    for (int t = 1; t < 8; ++t) {
        float4 ct = c[t];
        float o1 = ct.x, o2 = ct.z;
        int oj = __float_as_int(ct.y);
        float nb2 = fminf(fmaxf(b1, o1), fminf(b2, o2));
        if (o1 < b1 || (o1 == b1 && oj < j1)) { b1 = o1; j1 = oj; }
        b2 = nb2;
    }
    idxf[row] = (float)j1;
    float sq = 0.f;
    if (b2 - b1 >= VQ_MARGIN) {
#pragma unroll
        for (int lq = 0; lq < 16; ++lq) {
            float4 cv = *reinterpret_cast<const float4*>(&cb[(size_t)j1 * LAT_N + lq * 4]);
            float4 zv = *reinterpret_cast<const float4*>(&z[(size_t)row * LAT_N + lq * 4]);
            float d0 = cv.x - zv.x, d1 = cv.y - zv.y;
            float d2 = cv.z - zv.z, d3 = cv.w - zv.w;
            sq = fmaf(d0, d0, sq); sq = fmaf(d1, d1, sq);
            sq = fmaf(d2, d2, sq); sq = fmaf(d3, d3, sq);
        }
#pragma unroll
        for (int g = 0; g < 8; ++g) {
            int sp = pidx(j1, g * 8, LAT_N);
            int dp = pidx(row, g * 8, LAT_N);
            *reinterpret_cast<uint4*>(&zqhi[dp]) =
                *reinterpret_cast<const uint4*>(&cbhi[sp]);
            *reinterpret_cast<uint4*>(&zqlo[dp]) =
                *reinterpret_cast<const uint4*>(&cblo[sp]);
        }
    } else {
        int s = atomicAdd(rcnt, 1);
        if (s < B_ROWS) rlist[s] = row;
    }
    red[tid] = sq;
    __syncthreads();
    for (int off = 128; off > 0; off >>= 1) {
        if (tid < off) red[tid] += red[tid + off];
        __syncthreads();
    }
    if (tid == 0) mergep[blockIdx.x] = red[0];
}

// flagged rows: exact-f32 scan over compact zr; writes idx, packed z_q, loss
#define RB 8
__global__ __launch_bounds__(256) void repair_scan(
    const int* __restrict__ rcnt, const int* __restrict__ rlist,
    const float* __restrict__ zr,
    const float* __restrict__ cb, const float* __restrict__ cn,
    const unsigned short* __restrict__ cbhi,
    const unsigned short* __restrict__ cblo,
    unsigned short* __restrict__ zqhi, unsigned short* __restrict__ zqlo,
    float* __restrict__ idxf, float* __restrict__ repairp)
{
    __shared__ float sz[RB][LAT_N];
    __shared__ float rv[256];
    __shared__ int ri[256];
    const int tid = threadIdx.x;
    const int count = min(rcnt[0], B_ROWS);
    if (blockIdx.x * RB >= count) return;
    float lsum = 0.f;
    for (int base = blockIdx.x * RB; base < count; base += gridDim.x * RB) {
        int nr = min(RB, count - base);
        __syncthreads();
        for (int s = tid; s < nr * LAT_N; s += 256) {
            int r = s >> 6, d = s & 63;
            sz[r][d] = zr[(size_t)(base + r) * LAT_N + d];
        }
        __syncthreads();
        float bv[RB];
        int bj[RB];
#pragma unroll
        for (int r = 0; r < RB; ++r) { bv[r] = 3.4e38f; bj[r] = 0; }
        for (int k = 0; k < K_CB / 256; ++k) {
            int cidx = tid + k * 256;
            float a[RB];
#pragma unroll
            for (int r = 0; r < RB; ++r) a[r] = 0.f;
            const float* cp = &cb[(size_t)cidx * LAT_N];
#pragma unroll 2
            for (int d4 = 0; d4 < 16; ++d4) {
                float4 cv = *reinterpret_cast<const float4*>(cp + d4 * 4);
#pragma unroll
                for (int r = 0; r < RB; ++r) {
                    a[r] = fmaf(sz[r][d4 * 4 + 0], cv.x, a[r]);
                    a[r] = fmaf(sz[r][d4 * 4 + 1], cv.y, a[r]);
                    a[r] = fmaf(sz[r][d4 * 4 + 2], cv.z, a[r]);
                    a[r] = fmaf(sz[r][d4 * 4 + 3], cv.w, a[r]);
                }
            }
            float cnv = cn[cidx];
#pragma unroll
            for (int r = 0; r < RB; ++r) {
                float d = fmaf(-2.f, a[r], cnv);
                if (d < bv[r] || (d == bv[r] && cidx < bj[r])) {
                    bv[r] = d; bj[r] = cidx;
                }
            }
        }
        for (int r = 0; r < RB; ++r) {
            if (r >= nr) break;
            rv[tid] = bv[r];
            ri[tid] = bj[r];
            __syncthreads();
            for (int off = 128; off > 0; off >>= 1) {
                if (tid < off) {
                    float ov = rv[tid + off];
                    int oi = ri[tid + off];
                    if (ov < rv[tid] || (ov == rv[tid] && oi < ri[tid])) {
                        rv[tid] = ov; ri[tid] = oi;
                    }
                }
                __syncthreads();
            }
            int bjf = ri[0];
            int rr = rlist[base + r];
            bool ok = (unsigned)rr < (unsigned)B_ROWS;
            rr = ok ? rr : 0;
            if (tid == 0 && ok) idxf[rr] = (float)bjf;
            float v = 0.f;
            if (tid < 64) {
                float d = cb[(size_t)bjf * LAT_N + tid] - sz[r][tid];
                v = d * d;
            }
            __syncthreads();
            rv[tid] = v;
            __syncthreads();
            for (int off = 128; off > 0; off >>= 1) {
                if (tid < off) rv[tid] += rv[tid + off];
                __syncthreads();
            }
            if (tid == 0) lsum += rv[0];
            if (ok) {
                if (tid < 8) {
                    int g = tid;
                    *reinterpret_cast<uint4*>(&zqhi[pidx(rr, g * 8, LAT_N)]) =
                        *reinterpret_cast<const uint4*>(&cbhi[pidx(bjf, g * 8, LAT_N)]);
                } else if (tid < 16) {
                    int g = tid - 8;
                    *reinterpret_cast<uint4*>(&zqlo[pidx(rr, g * 8, LAT_N)]) =
                        *reinterpret_cast<const uint4*>(&cblo[pidx(bjf, g * 8, LAT_N)]);
                }
            }
            __syncthreads();
        }
    }
    if (tid == 0) repairp[blockIdx.x] = lsum;
}

__global__ __launch_bounds__(256) void finalize_kernel(
    const float* __restrict__ mergep, int nm,
    const float* __restrict__ repairp, int nr,
    const float* __restrict__ rep, int nre,
    float* __restrict__ vq_out, float* __restrict__ re_out)
{
    __shared__ float s[256];
    int tid = threadIdx.x;
    float a = 0.f;
    for (int i = tid; i < nm; i += 256) a += mergep[i];
    for (int i = tid; i < nr; i += 256) a += repairp[i];
    s[tid] = a;
    __syncthreads();
    for (int off = 128; off > 0; off >>= 1) {
        if (tid < off) s[tid] += s[tid + off];
        __syncthreads();
    }
    if (tid == 0) *vq_out = 1.25f * s[0] / (float)(B_ROWS * LAT_N);
    __syncthreads();
    float b = 0.f;
    for (int i = tid; i < nre; i += 256) b += rep[i];
    s[tid] = b;
    __syncthreads();
    for (int off = 128; off > 0; off >>= 1) {
        if (tid < off) s[tid] += s[tid + off];
        __syncthreads();
    }
    if (tid == 0) *re_out = s[0] / (float)(B_ROWS * D_IN);
}

extern "C" void kernel_launch(void* const* d_in, const int* in_sizes, int n_in,
                              void* d_out, int out_size, void* d_ws, size_t ws_size,
                              hipStream_t stream)
{
    const float* x    = (const float*)d_in[0];
    const float* ew1  = (const float*)d_in[1];
    const float* eb1  = (const float*)d_in[2];
    const float* eg1  = (const float*)d_in[3];
    const float* ebt1 = (const float*)d_in[4];
    const float* em1  = (const float*)d_in[5];
    const float* ev1  = (const float*)d_in[6];
    const float* ew2  = (const float*)d_in[7];
    const float* eb2  = (const float*)d_in[8];
    const float* eg2  = (const float*)d_in[9];
    const float* ebt2 = (const float*)d_in[10];
    const float* em2  = (const float*)d_in[11];
    const float* ev2  = (const float*)d_in[12];
    const float* ew3  = (const float*)d_in[13];
    const float* eb3  = (const float*)d_in[14];
    const float* cb   = (const float*)d_in[15];
    const float* dw1  = (const float*)d_in[16];
    const float* db1  = (const float*)d_in[17];
    const float* dg1  = (const float*)d_in[18];
    const float* dbt1 = (const float*)d_in[19];
    const float* dm1  = (const float*)d_in[20];
    const float* dv1  = (const float*)d_in[21];
    const float* dw2  = (const float*)d_in[22];
    const float* db2  = (const float*)d_in[23];
    const float* dg2  = (const float*)d_in[24];
    const float* dbt2 = (const float*)d_in[25];
    const float* dm2  = (const float*)d_in[26];
    const float* dv2  = (const float*)d_in[27];
    const float* dw3  = (const float*)d_in[28];
    const float* db3  = (const float*)d_in[29];

    float* outf = (float*)d_out;
    const size_t XR_OFF = 0;
    const size_t VQ_OFF = (size_t)B_ROWS * D_IN;
    const size_t IDX_OFF = VQ_OFF + 1;
    const size_t RE_OFF = IDX_OFF + B_ROWS;

    float* wsf = (float*)d_ws;
    size_t off = 0;
    float* buf256 = wsf + off; off += (size_t)B_ROWS * H1_N;
    float* buf128 = wsf + off; off += (size_t)B_ROWS * H2_N;
    float* zbuf   = wsf + off; off += (size_t)B_ROWS * LAT_N;
    float* zr     = wsf + off; off += (size_t)B_ROWS * LAT_N;
    float* cnbuf  = wsf + off; off += K_CB;
    float* mergep = wsf + off; off += 128;
    float* repairp= wsf + off; off += 256;
    float* rep    = wsf + off; off += 1024;
    unsigned short* cbhi = (unsigned short*)(wsf + off); off += K_CB * LAT_N / 2;
    unsigned short* cblo = (unsigned short*)(wsf + off); off += K_CB * LAT_N / 2;
    float4* candb = (float4*)(wsf + off); off += (size_t)B_ROWS * 8 * 4;
    int* rcnt  = (int*)(wsf + off); off += 16;
    int* rlist = (int*)(wsf + off); off += B_ROWS;
    unsigned short* w1hi = (unsigned short*)(wsf + off); off += (H2_N * LAT_N) / 2;
    unsigned short* w1lo = (unsigned short*)(wsf + off); off += (H2_N * LAT_N) / 2;
    unsigned short* w2hi = (unsigned short*)(wsf + off); off += (H1_N * H2_N) / 2;
    unsigned short* w2lo = (unsigned short*)(wsf + off); off += (H1_N * H2_N) / 2;
    unsigned short* w3hi = (unsigned short*)(wsf + off); off += (D_IN * H1_N) / 2;
    unsigned short* w3lo = (unsigned short*)(wsf + off); off += (D_IN * H1_N) / 2;
    unsigned short* e1hi = (unsigned short*)(wsf + off); off += (D_IN * H1_N) / 2;
    unsigned short* e1lo = (unsigned short*)(wsf + off); off += (D_IN * H1_N) / 2;
    unsigned short* e2hi = (unsigned short*)(wsf + off); off += (H1_N * H2_N) / 2;
    unsigned short* e2lo = (unsigned short*)(wsf + off); off += (H1_N * H2_N) / 2;
    unsigned short* e3hi = (unsigned short*)(wsf + off); off += (H2_N * LAT_N) / 2;
    unsigned short* e3lo = (unsigned short*)(wsf + off); off += (H2_N * LAT_N) / 2;
    unsigned short* zqhi = (unsigned short*)(wsf + off); off += (size_t)B_ROWS * LAT_N / 2;
    unsigned short* zqlo = (unsigned short*)(wsf + off); off += (size_t)B_ROWS * LAT_N / 2;

    // time-disjoint aliases (all packed layouts now):
    unsigned short* eh1hi = (unsigned short*)buf256;
    unsigned short* eh1lo = (unsigned short*)(buf256 + (size_t)B_ROWS * 128);
    unsigned short* zhi   = (unsigned short*)buf256;
    unsigned short* zlo   = (unsigned short*)(buf256 + (size_t)B_ROWS * 32);
    float*          h1r   = buf256;
    unsigned short* dh2hi = (unsigned short*)buf256;
    unsigned short* dh2lo = (unsigned short*)(buf256 + (size_t)B_ROWS * 128);
    unsigned short* eh2hi = (unsigned short*)buf128;
    unsigned short* eh2lo = (unsigned short*)(buf128 + (size_t)B_ROWS * 64);
    float*          h2r   = buf128;
    unsigned short* dh1hi = (unsigned short*)buf128;
    unsigned short* dh1lo = (unsigned short*)(buf128 + (size_t)B_ROWS * 64);

    dim3 blk(256);
    const int GXM = B_ROWS / 128;   // 256
    const int GM64 = B_ROWS / 64;   // 512

    prep_all<<<dim3(176), blk, 0, stream>>>(
        dw3, w3hi, w3lo, dw2, w2hi, w2lo, dw1, w1hi, w1lo,
        ew1, e1hi, e1lo, ew2, e2hi, e2lo, ew3, e3hi, e3lo,
        cb, cbhi, cblo, cnbuf, rcnt, repairp);

    // encoder (bf16x3 MFMA, packed operands)
    mfma_gemm<0, D_IN, 4, true><<<dim3(GXM, H1_N / 128), blk, 0, stream>>>(
        x, nullptr, nullptr, e1hi, e1lo, eb1, eg1, ebt1, em1, ev1,
        eh1hi, eh1lo, nullptr, nullptr, nullptr, H1_N);
    mfma_gemm<0, H1_N, 4, false><<<dim3(GXM, 1), blk, 0, stream>>>(
        nullptr, eh1hi, eh1lo, e2hi, e2lo, eb2, eg2, ebt2, em2, ev2,
        eh2hi, eh2lo, nullptr, nullptr, nullptr, H2_N);
    mfma_gemm<3, H2_N, 2, false><<<dim3(GXM, 1), blk, 0, stream>>>(
        nullptr, eh2hi, eh2lo, e3hi, e3lo, eb3, nullptr, nullptr, nullptr, nullptr,
        zhi, zlo, zbuf, nullptr, nullptr, LAT_N);

    // vector quantization
    vq_mfma<<<dim3(1024), blk, 0, stream>>>(zhi, zlo, cbhi, cblo, cnbuf, candb);
    vq_merge<<<dim3(B_ROWS / 256), blk, 0, stream>>>(
        candb, zbuf, cb, cbhi, cblo, zqhi, zqlo,
        outf + IDX_OFF, rlist, rcnt, mergep);

    // repair: exact f32 encoder on flagged rows + exact scan
    rgemm<0, true><<<dim3(GM64, 2), blk, 0, stream>>>(
        rcnt, rlist, x, ew1, eb1, eg1, ebt1, em1, ev1, h1r, D_IN, H1_N);
    rgemm<0, false><<<dim3(GM64, 1), blk, 0, stream>>>(
        rcnt, rlist, h1r, ew2, eb2, eg2, ebt2, em2, ev2, h2r, H1_N, H2_N);
    rgemm<1, false><<<dim3(GM64, 1), blk, 0, stream>>>(
        rcnt, rlist, h2r, ew3, eb3, nullptr, nullptr, nullptr, nullptr,
        zr, H2_N, LAT_N);
    repair_scan<<<dim3(256), blk, 0, stream>>>(
        rcnt, rlist, zr, cb, cnbuf, cbhi, cblo, zqhi, zqlo,
        outf + IDX_OFF, repairp);

    // decoder (bf16x3 MFMA, packed operands)
    mfma_gemm<0, LAT_N, 4, false><<<dim3(GXM, 1), blk, 0, stream>>>(
        nullptr, zqhi, zqlo, w1hi, w1lo, db1, dg1, dbt1, dm1, dv1,
        dh1hi, dh1lo, nullptr, nullptr, nullptr, H2_N);
    mfma_gemm<0, H2_N, 4, false><<<dim3(GXM, H1_N / 128), blk, 0, stream>>>(
        nullptr, dh1hi, dh1lo, w2hi, w2lo, db2, dg2, dbt2, dm2, dv2,
        dh2hi, dh2lo, nullptr, nullptr, nullptr, H1_N);
    mfma_gemm<2, H1_N, 4, false><<<dim3(GXM, D_IN / 128), blk, 0, stream>>>(
        nullptr, dh2hi, dh2lo, w3hi, w3lo, db3, nullptr, nullptr, nullptr, nullptr,
        nullptr, nullptr, outf + XR_OFF, x, rep, D_IN);

    finalize_kernel<<<dim3(1), blk, 0, stream>>>(
        mergep, 128, repairp, 256, rep, 1024, outf + VQ_OFF, outf + RE_OFF);
}